// Round 9
// baseline (382.404 us; speedup 1.0000x reference)
//
#include <hip/hip_runtime.h>
#include <hip/hip_fp16.h>

#define N_NODES 100000
#define N_EDGES 1600000
#define IN_F 128
#define H_F 64

#define NCHUNK 64
#define CHUNK_E (N_EDGES / NCHUNK)      // 25000

// histogram slicing: 2x u16 packed per u32 -> 25000 nodes in 50KB LDS
#define NSLICE_H 4
#define SLICE_H (N_NODES / NSLICE_H)    // 25000
// scatter slicing: u32 cursors -> 12500 nodes in 50KB LDS
#define NSLICE_S 8
#define SLICE_S (N_NODES / NSLICE_S)    // 12500

// ---------------- LDS histogram, packed u16 pairs; y=0 -> dst, y=1 -> src ----------------
__global__ __launch_bounds__(256) void hist_both_kernel(
        const int* __restrict__ dst, const int* __restrict__ src,
        unsigned* __restrict__ pdst, unsigned* __restrict__ psrc) {
    __shared__ unsigned hist[SLICE_H / 2];
    const int* idx = blockIdx.y ? src : dst;
    unsigned* partial = blockIdx.y ? psrc : pdst;
    int slice = blockIdx.x & (NSLICE_H - 1);
    int chunk = blockIdx.x >> 2;
    int lo = slice * SLICE_H;
    for (int t = threadIdx.x; t < SLICE_H / 2; t += 256) hist[t] = 0;
    __syncthreads();
    int e0 = chunk * CHUNK_E;
    for (int e = e0 + threadIdx.x; e < e0 + CHUNK_E; e += 256) {
        int d = idx[e] - lo;
        if ((unsigned)d < (unsigned)SLICE_H)
            atomicAdd(&hist[d >> 1], 1u << ((d & 1) << 4));
    }
    __syncthreads();
    unsigned* dstp = partial + (size_t)chunk * (N_NODES / 2) + (lo >> 1);
    for (int t = threadIdx.x; t < SLICE_H / 2; t += 256) dstp[t] = hist[t];
}

// ---------------- reduce partials -> norms + block-level scan of deg_dst ----------------
__global__ void reduce_norm_scan_kernel(const unsigned* __restrict__ psrc,
                                        const unsigned* __restrict__ pdst,
                                        float* __restrict__ out_norm, float* __restrict__ in_norm,
                                        int* __restrict__ row_off, int* __restrict__ bsums, int N) {
    __shared__ int temp[256];
    int tid = threadIdx.x;
    int i = blockIdx.x * 256 + tid;
    int ds = 0, dd = 0;
    if (i < N) {
        int half = i >> 1, sh = (i & 1) << 4;
#pragma unroll
        for (int c = 0; c < NCHUNK; c++) {
            ds += (psrc[(size_t)c * (N_NODES / 2) + half] >> sh) & 0xFFFF;
            dd += (pdst[(size_t)c * (N_NODES / 2) + half] >> sh) & 0xFFFF;
        }
        out_norm[i] = rsqrtf((float)max(ds, 1));
        in_norm[i]  = rsqrtf((float)max(dd, 1));
    }
    temp[tid] = dd;
    __syncthreads();
    for (int off = 1; off < 256; off <<= 1) {
        int t = (tid >= off) ? temp[tid - off] : 0;
        __syncthreads();
        temp[tid] += t;
        __syncthreads();
    }
    int excl = (tid > 0) ? temp[tid - 1] : 0;
    if (i < N) row_off[i] = excl;
    if (tid == 255) bsums[blockIdx.x] = temp[255];
}

__global__ void scan_sums_kernel(int* __restrict__ bsums, int B) {
    __shared__ int temp[512];
    int tid = threadIdx.x;
    int v = (tid < B) ? bsums[tid] : 0;
    temp[tid] = v;
    __syncthreads();
    for (int off = 1; off < 512; off <<= 1) {
        int t = (tid >= off) ? temp[tid - off] : 0;
        __syncthreads();
        temp[tid] += t;
        __syncthreads();
    }
    int excl = (tid > 0) ? temp[tid - 1] : 0;
    if (tid < B) bsums[tid] = excl;
}

// ---------------- finalize row_off + emit per-chunk base cursors ----------------
__global__ void scan_add_base_kernel(int* __restrict__ row_off, const int* __restrict__ bsums,
                                     const unsigned* __restrict__ pdst, int* __restrict__ base,
                                     int N, int E) {
    int i = blockIdx.x * 256 + threadIdx.x;
    if (i < N) {
        int r = row_off[i] + bsums[i >> 8];
        row_off[i] = r;
        int half = i >> 1, sh = (i & 1) << 4;
        int b = r;
#pragma unroll
        for (int c = 0; c < NCHUNK; c++) {
            int t = (pdst[(size_t)c * (N_NODES / 2) + half] >> sh) & 0xFFFF;
            base[(size_t)c * N_NODES + i] = b;
            b += t;
        }
    }
    if (i == 0) row_off[N] = E;
}

// ---------------- counting-sort scatter: LDS cursors, plain global stores ----------------
__global__ __launch_bounds__(256) void scatter_sort_kernel(
        const int* __restrict__ src, const int* __restrict__ dst,
        const int* __restrict__ base, int* __restrict__ csr_src) {
    __shared__ int cur[SLICE_S];
    int slice = blockIdx.x & (NSLICE_S - 1);
    int chunk = blockIdx.x >> 3;
    int lo = slice * SLICE_S;
    const int* bp = base + (size_t)chunk * N_NODES + lo;
    for (int t = threadIdx.x; t < SLICE_S; t += 256) cur[t] = bp[t];
    __syncthreads();
    int e0 = chunk * CHUNK_E;
    for (int e = e0 + threadIdx.x; e < e0 + CHUNK_E; e += 256) {
        int d = dst[e] - lo;
        if ((unsigned)d < (unsigned)SLICE_S) {
            int p = atomicAdd(&cur[d], 1);   // LDS atomic
            csr_src[p] = src[e];
        }
    }
}

// ---------------- thread-per-row GEMM, fp16 output, 32-col half per blockIdx.y ----------------
template <int K, typename TIN>
__global__ __launch_bounds__(256, 4) void gemm_tpr_kernel(
        const TIN* __restrict__ in, const float* __restrict__ W,
        const float* __restrict__ scale, __half* __restrict__ out, int N) {
    int r = blockIdx.x * blockDim.x + threadIdx.x;
    if (r >= N) return;
    const int h = blockIdx.y * 32;

    float acc[32];
#pragma unroll
    for (int j = 0; j < 32; j++) acc[j] = 0.f;

    const TIN* row = in + (size_t)r * K;
#pragma unroll 4
    for (int k = 0; k < K; k += 4) {
        float ax, ay, az, aw;
        if constexpr (sizeof(TIN) == 4) {
            float4 a = *reinterpret_cast<const float4*>(row + k);
            ax = a.x; ay = a.y; az = a.z; aw = a.w;
        } else {
            __half2 h0 = *reinterpret_cast<const __half2*>(row + k);
            __half2 h1 = *reinterpret_cast<const __half2*>(row + k + 2);
            ax = __low2float(h0); ay = __high2float(h0);
            az = __low2float(h1); aw = __high2float(h1);
        }
        const float* w0 = W + (size_t)k * 64 + h;
#pragma unroll
        for (int j = 0; j < 32; j++) acc[j] = fmaf(ax, w0[j], acc[j]);
#pragma unroll
        for (int j = 0; j < 32; j++) acc[j] = fmaf(ay, w0[64 + j], acc[j]);
#pragma unroll
        for (int j = 0; j < 32; j++) acc[j] = fmaf(az, w0[128 + j], acc[j]);
#pragma unroll
        for (int j = 0; j < 32; j++) acc[j] = fmaf(aw, w0[192 + j], acc[j]);
    }

    float s = scale[r];
    __half2 hv[16];
#pragma unroll
    for (int j = 0; j < 16; j++)
        hv[j] = __halves2half2(__float2half_rn(acc[2 * j] * s),
                               __float2half_rn(acc[2 * j + 1] * s));
    uint4* o = reinterpret_cast<uint4*>(out + (size_t)r * 64 + h);
    const uint4* hvp = reinterpret_cast<const uint4*>(hv);
#pragma unroll
    for (int j = 0; j < 4; j++) o[j] = hvp[j];
}

// ---------------- CSR aggregation: fp16 gathers, scalar index loads, 16-deep batching ----------------
template <bool FUSE_HEAD>
__global__ __launch_bounds__(256) void agg_kernel(
        const __half* __restrict__ X, const int* __restrict__ row_off,
        const int* __restrict__ csr_src, const float* __restrict__ in_norm,
        const float* __restrict__ bias, const float* __restrict__ Wm,
        const float* __restrict__ bm, __half* __restrict__ outh,
        float* __restrict__ outf, int N) {
    int lane = threadIdx.x & 63;
    int wave = threadIdx.x >> 6;
    int v = blockIdx.x * (blockDim.x >> 6) + wave;
    if (v >= N) return;

    int start = __builtin_amdgcn_readfirstlane(row_off[v]);
    int end   = __builtin_amdgcn_readfirstlane(row_off[v + 1]);
    int deg = end - start;
    const int* __restrict__ idxp = csr_src + start;

    float acc0 = 0.f, acc1 = 0.f;
    int t = 0;
    for (; t + 16 <= deg; t += 16) {
        int s[16];
#pragma unroll
        for (int u = 0; u < 16; u++) s[u] = idxp[t + u];
        __half a[16];
#pragma unroll
        for (int u = 0; u < 16; u++) a[u] = X[(size_t)s[u] * 64 + lane];
        float f[16];
#pragma unroll
        for (int u = 0; u < 16; u++) f[u] = __half2float(a[u]);
        acc0 += (((f[0] + f[1]) + (f[2] + f[3])) + ((f[4] + f[5]) + (f[6] + f[7])));
        acc1 += (((f[8] + f[9]) + (f[10] + f[11])) + ((f[12] + f[13]) + (f[14] + f[15])));
    }
    for (; t + 8 <= deg; t += 8) {
        int s[8];
#pragma unroll
        for (int u = 0; u < 8; u++) s[u] = idxp[t + u];
        __half a[8];
#pragma unroll
        for (int u = 0; u < 8; u++) a[u] = X[(size_t)s[u] * 64 + lane];
        float f[8];
#pragma unroll
        for (int u = 0; u < 8; u++) f[u] = __half2float(a[u]);
        acc0 += (((f[0] + f[1]) + (f[2] + f[3])) + ((f[4] + f[5]) + (f[6] + f[7])));
    }
    for (; t < deg; t++) {
        int s = idxp[t];
        acc0 += __half2float(X[(size_t)s * 64 + lane]);
    }
    float acc = acc0 + acc1;

    float h = fmaf(acc, in_norm[v], bias[lane]);
    h = fmaxf(h, 0.f);

    if (!FUSE_HEAD) {
        outh[(size_t)v * 64 + lane] = __float2half_rn(h);
    } else {
        float p0 = h * Wm[lane * 2 + 0];
        float p1 = h * Wm[lane * 2 + 1];
#pragma unroll
        for (int off = 32; off > 0; off >>= 1) {
            p0 += __shfl_xor(p0, off);
            p1 += __shfl_xor(p1, off);
        }
        if (lane == 0) {
            outf[(size_t)v * 2 + 0] = p0 + bm[0];
            outf[(size_t)v * 2 + 1] = p1 + bm[1];
        }
    }
}

extern "C" void kernel_launch(void* const* d_in, const int* in_sizes, int n_in,
                              void* d_out, int out_size, void* d_ws, size_t ws_size,
                              hipStream_t stream) {
    const float* feature = (const float*)d_in[0];
    const float* W1 = (const float*)d_in[1];
    const float* b1 = (const float*)d_in[2];
    const float* W2 = (const float*)d_in[3];
    const float* b2 = (const float*)d_in[4];
    const float* Wm = (const float*)d_in[5];
    const float* bm = (const float*)d_in[6];
    const int* src = (const int*)d_in[7];
    const int* dst = (const int*)d_in[8];
    float* out = (float*)d_out;

    const int N = N_NODES, E = N_EDGES;

    char* p = (char*)d_ws;
    float* out_norm = (float*)p; p += (size_t)N * 4;
    float* in_norm = (float*)p;  p += (size_t)N * 4;
    int* row_off = (int*)p;      p += (size_t)(N + 1) * 4;
    int* bsums = (int*)p;        p += 512 * 4;
    int* csr_src = (int*)p;      p += (size_t)E * 4;
    __half* X = (__half*)p;      p += (size_t)N * 64 * 2;   // 12.8 MB
    __half* H = (__half*)p;      p += (size_t)N * 64 * 2;   // 12.8 MB
    unsigned* pdst = (unsigned*)p; p += (size_t)NCHUNK * (N_NODES / 2) * 4;  // 12.8 MB
    unsigned* psrc = (unsigned*)p; p += (size_t)NCHUNK * (N_NODES / 2) * 4;  // 12.8 MB

    // base [NCHUNK][N] = 25.6 MB aliases X∪H (consumed by scatter before gemm1 writes X)
    int* base = (int*)X;

    dim3 hgrid(NSLICE_H * NCHUNK, 2);
    hist_both_kernel<<<hgrid, 256, 0, stream>>>(dst, src, pdst, psrc);

    int nScanBlocks = (N + 255) / 256;  // 391
    reduce_norm_scan_kernel<<<nScanBlocks, 256, 0, stream>>>(psrc, pdst, out_norm, in_norm,
                                                             row_off, bsums, N);
    scan_sums_kernel<<<1, 512, 0, stream>>>(bsums, nScanBlocks);
    scan_add_base_kernel<<<nScanBlocks, 256, 0, stream>>>(row_off, bsums, pdst, base, N, E);

    scatter_sort_kernel<<<NSLICE_S * NCHUNK, 256, 0, stream>>>(src, dst, base, csr_src);

    dim3 ggrid((N + 255) / 256, 2);
    // layer 1
    gemm_tpr_kernel<128, float><<<ggrid, 256, 0, stream>>>(feature, W1, out_norm, X, N);
    agg_kernel<false><<<(N + 3) / 4, 256, 0, stream>>>(X, row_off, csr_src, in_norm, b1,
                                                       nullptr, nullptr, H, nullptr, N);
    // layer 2
    gemm_tpr_kernel<64, __half><<<ggrid, 256, 0, stream>>>(H, W2, out_norm, X, N);
    // fused head
    agg_kernel<true><<<(N + 3) / 4, 256, 0, stream>>>(X, row_off, csr_src, in_norm, b2,
                                                      Wm, bm, nullptr, out, N);
}